// Round 1
// baseline (2023.930 us; speedup 1.0000x reference)
//
#include <hip/hip_runtime.h>
#include <math.h>

// Problem constants
#define BB   32
#define CIN  16
#define C1   72      // (16+2)*2*2
#define NTOK 1024    // 32*32
#define HH   64
#define WW2  64

// ---------------------------------------------------------------------------
// Kernel 1: coord-concat + pixel_unshuffle -> t [B,72,1024]; per-token
// channel-norm -> tn. One thread per (b, token).
// ---------------------------------------------------------------------------
__global__ __launch_bounds__(256) void k1_build(const float* __restrict__ x,
                                                float* __restrict__ t,
                                                float* __restrict__ tn) {
  int gid = blockIdx.x * 256 + threadIdx.x;   // 32768 threads
  int b = gid >> 10;
  int n = gid & 1023;
  int hh = n >> 5, ww = n & 31;
  float vals[C1];
  float ss = 0.f;
#pragma unroll
  for (int c1 = 0; c1 < C1; ++c1) {
    int c = c1 >> 2, sh = (c1 >> 1) & 1, sw = c1 & 1;
    int h = 2 * hh + sh, w = 2 * ww + sw;
    float val;
    if (c < CIN) {
      val = x[((b * CIN + c) * HH + h) * WW2 + w];
    } else {
      float r = fmaxf(sqrtf((float)(h * h + w * w)), 1e-12f);
      val = (c == CIN ? (float)h : (float)w) / r;
    }
    vals[c1] = val;
    ss += val * val;
  }
  float inv = 1.0f / fmaxf(sqrtf(ss), 1e-12f);
#pragma unroll
  for (int c1 = 0; c1 < C1; ++c1) {
    int o = (b * C1 + c1) * NTOK + n;
    t[o]  = vals[c1];
    tn[o] = vals[c1] * inv;
  }
}

// ---------------------------------------------------------------------------
// Kernel 2: V = t @ Wv^T + bv.  A [2304][1024] (K contiguous), Wv [1024][1024]
// (K contiguous) -> NT GEMM. 64x64 tile, BK=16, 256 threads, 4x4 micro-tile
// (cols strided by 16 to avoid LDS quad-bank conflicts on b128 reads).
// ---------------------------------------------------------------------------
#define K2_BK 16
__global__ __launch_bounds__(256) void k2_vproj(const float* __restrict__ A,
                                                const float* __restrict__ Wv,
                                                const float* __restrict__ bv,
                                                float* __restrict__ V) {
  __shared__ float As[64][K2_BK + 4];   // row stride 20 dwords = 80B (16B mult)
  __shared__ float Bs[64][K2_BK + 4];
  int tid = threadIdx.x;
  int row0 = blockIdx.x * 64;   // 36 blocks
  int col0 = blockIdx.y * 64;   // 16 blocks
  int tx = tid & 15, ty = tid >> 4;
  int lr = tid >> 2;            // 0..63
  int lk = (tid & 3) << 2;      // 0,4,8,12
  float acc[4][4];
#pragma unroll
  for (int i = 0; i < 4; ++i)
#pragma unroll
    for (int j = 0; j < 4; ++j) acc[i][j] = 0.f;

  for (int kt = 0; kt < 1024; kt += K2_BK) {
    float4 a4 = *(const float4*)&A[(row0 + lr) * 1024 + kt + lk];
    float4 b4 = *(const float4*)&Wv[(col0 + lr) * 1024 + kt + lk];
    *(float4*)&As[lr][lk] = a4;
    *(float4*)&Bs[lr][lk] = b4;
    __syncthreads();
#pragma unroll
    for (int kq = 0; kq < K2_BK; kq += 4) {
      float4 a[4], bbv[4];
#pragma unroll
      for (int i = 0; i < 4; ++i) a[i] = *(const float4*)&As[ty * 4 + i][kq];
#pragma unroll
      for (int j = 0; j < 4; ++j) bbv[j] = *(const float4*)&Bs[tx + 16 * j][kq];
#pragma unroll
      for (int i = 0; i < 4; ++i)
#pragma unroll
        for (int j = 0; j < 4; ++j)
          acc[i][j] += a[i].x * bbv[j].x + a[i].y * bbv[j].y +
                       a[i].z * bbv[j].z + a[i].w * bbv[j].w;
    }
    __syncthreads();
  }
#pragma unroll
  for (int i = 0; i < 4; ++i) {
    int r = row0 + ty * 4 + i;
#pragma unroll
    for (int j = 0; j < 4; ++j) {
      int cidx = col0 + tx + 16 * j;
      V[r * 1024 + cidx] = acc[i][j] + bv[cidx];
    }
  }
}

// ---------------------------------------------------------------------------
// Kernel 3: cosine-sim rows + online top-3 + softmax. Block = 512 threads =
// 64 rows x 8 m-splits. tn tiles of 64 m staged in LDS; per-thread online
// top-3 with jax.lax.top_k-stable comparator; 8-way merge via LDS.
// ---------------------------------------------------------------------------
__global__ __launch_bounds__(512) void k3_topk(const float* __restrict__ tn,
                                               int* __restrict__ idxo,
                                               float* __restrict__ attno) {
  __shared__ float tile[C1][64];
  __shared__ float mv[512 * 3];
  __shared__ int   mi[512 * 3];
  int b  = blockIdx.y;
  int n0 = blockIdx.x * 64;
  int tid = threadIdx.x;
  int s = tid >> 6, r = tid & 63;
  int n = n0 + r;

  float tnrow[C1];
#pragma unroll
  for (int c = 0; c < C1; ++c) tnrow[c] = tn[(b * C1 + c) * NTOK + n];

  float v0 = -INFINITY, v1 = -INFINITY, v2 = -INFINITY;
  int   i0 = 0x7fffffff, i1 = 0x7fffffff, i2 = 0x7fffffff;
  auto ins = [&](float d, int di) {
    if (d > v0 || (d == v0 && di < i0)) {
      v2 = v1; i2 = i1; v1 = v0; i1 = i0; v0 = d; i0 = di;
    } else if (d > v1 || (d == v1 && di < i1)) {
      v2 = v1; i2 = i1; v1 = d; i1 = di;
    } else if (d > v2 || (d == v2 && di < i2)) {
      v2 = d; i2 = di;
    }
  };

  for (int tl = 0; tl < 16; ++tl) {
    int m0 = tl * 64;
    __syncthreads();   // previous tile fully consumed
    for (int e4 = tid; e4 < C1 * 16; e4 += 512) {
      int c = e4 >> 4, mq = e4 & 15;
      float4 val = *(const float4*)&tn[(b * C1 + c) * NTOK + m0 + mq * 4];
      *(float4*)&tile[c][mq * 4] = val;
    }
    __syncthreads();
#pragma unroll
    for (int q = 0; q < 2; ++q) {
      int mm = s * 8 + q * 4;
      float d0 = 0.f, d1 = 0.f, d2 = 0.f, d3 = 0.f;
#pragma unroll
      for (int c = 0; c < C1; ++c) {
        float a = tnrow[c];
        float4 tv = *(const float4*)&tile[c][mm];
        d0 += a * tv.x; d1 += a * tv.y; d2 += a * tv.z; d3 += a * tv.w;
      }
      int mg = m0 + mm;
      ins(d0, mg); ins(d1, mg + 1); ins(d2, mg + 2); ins(d3, mg + 3);
    }
  }
  int base = (r * 8 + s) * 3;
  mv[base] = v0; mv[base + 1] = v1; mv[base + 2] = v2;
  mi[base] = i0; mi[base + 1] = i1; mi[base + 2] = i2;
  __syncthreads();
  if (tid < 64) {
    v0 = v1 = v2 = -INFINITY;
    i0 = i1 = i2 = 0x7fffffff;
    for (int s2 = 0; s2 < 8; ++s2) {
#pragma unroll
      for (int j = 0; j < 3; ++j) {
        int bi = (tid * 8 + s2) * 3 + j;
        ins(mv[bi], mi[bi]);
      }
    }
    float e1 = expf(v1 - v0), e2 = expf(v2 - v0);
    float inv = 1.0f / (1.0f + e1 + e2);
    int nn = n0 + tid;
    int ob = (b * NTOK + nn) * 3;
    idxo[ob] = i0; idxo[ob + 1] = i1; idxo[ob + 2] = i2;
    attno[ob] = inv; attno[ob + 1] = e1 * inv; attno[ob + 2] = e2 * inv;
  }
}

// ---------------------------------------------------------------------------
// Kernel 4: gather top-3 neighbor value columns (x attn) into LDS, then
// conv1d(kernel=K,stride=K) == [72 x 216] GEMM per token. Block = 64 tokens,
// 4 waves x 18 output channels; conv_w addresses wave-uniform (scalar loads).
// ---------------------------------------------------------------------------
__global__ __launch_bounds__(256) void k4_conv1d(const float* __restrict__ v,
                                                 const int* __restrict__ idx,
                                                 const float* __restrict__ attn,
                                                 const float* __restrict__ conv_w,
                                                 const float* __restrict__ conv_b,
                                                 float* __restrict__ out1d) {
  __shared__ float prime[64][220];   // pad 220: aligned b128 rows, spread quads
  __shared__ int   sidx[64][3];
  __shared__ float satt[64][3];
  int b  = blockIdx.y;
  int n0 = blockIdx.x * 64;
  int tid = threadIdx.x;
  if (tid < 192) {
    int tok = tid / 3, k = tid % 3;
    sidx[tok][k] = idx[(b * NTOK + n0 + tok) * 3 + k];
    satt[tok][k] = attn[(b * NTOK + n0 + tok) * 3 + k];
  }
  __syncthreads();
  for (int e = tid; e < 64 * 216; e += 256) {
    int tok = e & 63, ck = e >> 6;
    int c = ck / 3, k = ck - c * 3;
    prime[tok][ck] = v[(b * C1 + c) * NTOK + sidx[tok][k]] * satt[tok][k];
  }
  __syncthreads();
  int tok = tid & 63;
  int obase = __builtin_amdgcn_readfirstlane((int)(tid >> 6)) * 18;
  float acc[18];
#pragma unroll
  for (int j = 0; j < 18; ++j) acc[j] = 0.f;
  for (int ck4 = 0; ck4 < 54; ++ck4) {
    float4 p4 = *(const float4*)&prime[tok][ck4 * 4];
#pragma unroll
    for (int j = 0; j < 18; ++j) {
      float4 w4 = *(const float4*)&conv_w[(obase + j) * 216 + ck4 * 4];
      acc[j] += p4.x * w4.x + p4.y * w4.y + p4.z * w4.z + p4.w * w4.w;
    }
  }
#pragma unroll
  for (int j = 0; j < 18; ++j) {
    int o = obase + j;
    out1d[(b * C1 + o) * NTOK + n0 + tok] = acc[j] + conv_b[o];
  }
}

// ---------------------------------------------------------------------------
// Kernel 5: pixel_shuffle + pointwise 1x1 conv. One thread per (b,h,w) pixel,
// computes all 16 output channels (reads each out1d element exactly once).
// ---------------------------------------------------------------------------
__global__ __launch_bounds__(256) void k5_pw(const float* __restrict__ out1d,
                                             const float* __restrict__ pw_w,
                                             const float* __restrict__ pw_b,
                                             float* __restrict__ out) {
  int gid = blockIdx.x * 256 + threadIdx.x;   // 131072 threads
  int b = gid >> 12;
  int p = gid & 4095;
  int h = p >> 6, w = p & 63;
  int hh = h >> 1, ww = w >> 1;
  int c1base = ((h & 1) << 1) | (w & 1);
  int n = hh * 32 + ww;
  float xs[18];
#pragma unroll
  for (int c = 0; c < 18; ++c)
    xs[c] = out1d[(b * C1 + c * 4 + c1base) * NTOK + n];
#pragma unroll
  for (int o = 0; o < 16; ++o) {
    float a = pw_b[o];
#pragma unroll
    for (int c = 0; c < 18; ++c) a += xs[c] * pw_w[o * 18 + c];
    out[((b * 16 + o) << 12) + p] = a;
  }
}

// ---------------------------------------------------------------------------
extern "C" void kernel_launch(void* const* d_in, const int* in_sizes, int n_in,
                              void* d_out, int out_size, void* d_ws, size_t ws_size,
                              hipStream_t stream) {
  (void)in_sizes; (void)n_in; (void)out_size; (void)ws_size;
  const float* x      = (const float*)d_in[0];
  const float* Wv     = (const float*)d_in[1];
  const float* bv     = (const float*)d_in[2];
  const float* conv_w = (const float*)d_in[3];
  const float* conv_b = (const float*)d_in[4];
  const float* pw_w   = (const float*)d_in[5];
  const float* pw_b   = (const float*)d_in[6];
  float* out = (float*)d_out;

  // workspace layout (38.5 MB total)
  const size_t SZ_T = (size_t)BB * C1 * NTOK * sizeof(float);   // 9,437,184
  char* ws = (char*)d_ws;
  float* t     = (float*)(ws);
  float* tn    = (float*)(ws + SZ_T);
  float* v     = (float*)(ws + 2 * SZ_T);
  int*   idx   = (int*)  (ws + 3 * SZ_T);
  float* attn  = (float*)(ws + 3 * SZ_T + 393216);
  float* out1d = (float*)(ws + 3 * SZ_T + 2 * 393216);

  k1_build<<<dim3((BB * NTOK) / 256), 256, 0, stream>>>(x, t, tn);
  k2_vproj<<<dim3(36, 16), 256, 0, stream>>>(t, Wv, bv, v);
  k3_topk <<<dim3(16, BB), 512, 0, stream>>>(tn, idx, attn);
  k4_conv1d<<<dim3(16, BB), 256, 0, stream>>>(v, idx, attn, conv_w, conv_b, out1d);
  k5_pw   <<<dim3((BB * 4096) / 256), 256, 0, stream>>>(out1d, pw_w, pw_b, out);
}